// Round 2
// baseline (260.881 us; speedup 1.0000x reference)
//
#include <hip/hip_runtime.h>

#define T_LEN 1024
#define N_DIM 256
#define EPL 4  // elements per lane (256 / 64)

// Wave64 full reduction level via DPP (VALU pipe, ~4cyc dependent latency,
// vs ds_swizzle/bpermute ~100+cyc on the LDS pipe).
template<int CTRL>
__device__ __forceinline__ float dpp_add_f32(float v) {
    int mv = __builtin_amdgcn_update_dpp(0, __float_as_int(v), CTRL, 0xf, 0xf, true);
    return v + __int_as_float(mv);
}

// One wave (64 lanes) per batch element; 4 waves per 256-thread block.
// B=1024 waves total = 1 wave per SIMD on MI355X (256 CU x 4 SIMD).
__global__ __launch_bounds__(256, 1) void rnn_lowrank_kernel(
    const float* __restrict__ u,   // (B, T)
    const float* __restrict__ m,   // (N, 2) row-major
    const float* __restrict__ n,   // (N, 2) row-major
    const float* __restrict__ wi,  // (N,)
    const float* __restrict__ w,   // (N, 1)
    float* __restrict__ z)         // (B, T)
{
    __shared__ float u_lds[4][T_LEN];

    const int wave = threadIdx.x >> 6;
    const int lane = threadIdx.x & 63;
    const int b    = (blockIdx.x << 2) + wave;

    // ---- stage this wave's u row into LDS (4 KB), coalesced float4 loads ----
    {
        const float4* src = reinterpret_cast<const float4*>(u + (size_t)b * T_LEN);
        float4*       dst = reinterpret_cast<float4*>(&u_lds[wave][0]);
#pragma unroll
        for (int k = 0; k < 4; ++k)
            dst[lane + (k << 6)] = src[lane + (k << 6)];
    }

    // ---- weights into registers; fold all constants ----
    // Track y = c*x with c = 2*log2(e), so tanh arg is exp2(y) directly:
    //   y_new = 0.8*y + a0*(c*dt/N*m0) + a1*(c*dt/N*m1) + u_t*(c*dt*wi)
    //   r     = 1 - 2/(exp2(y_new)+1)   (== tanh(x_new), saturates right at +-inf)
    //   z_t   = sum_j r_j * (w_j/N)
    const float invN = 1.0f / (float)N_DIM;
    const float dt   = 0.2f;
    const float c    = 2.8853900817779268f;  // 2*log2(e)
    float m0f[EPL], m1f[EPL], n0r[EPL], n1r[EPL], wf[EPL], wif[EPL];
#pragma unroll
    for (int e = 0; e < EPL; ++e) {
        int j = lane + (e << 6);
        m0f[e] = m[2 * j + 0] * (invN * dt * c);
        m1f[e] = m[2 * j + 1] * (invN * dt * c);
        n0r[e] = n[2 * j + 0];
        n1r[e] = n[2 * j + 1];
        wf[e]  = w[j] * invN;
        wif[e] = wi[j] * (dt * c);
    }

    float y[EPL];
#pragma unroll
    for (int e = 0; e < EPL; ++e) y[e] = 0.0f;

    float a0 = 0.0f, a1 = 0.0f;   // wave sums of r_t * n (r_0 = tanh(0) = 0)
    float zbuf = 0.0f;            // per-lane captured z value (one per 64 steps)
    float u_cur = u_lds[wave][0];

    for (int t = 0; t < T_LEN; ++t) {
        // prefetch next u (broadcast LDS read; wraps harmlessly on last iter)
        float u_next = u_lds[wave][(t + 1) & (T_LEN - 1)];

        float p0 = 0.0f, p1 = 0.0f, pz = 0.0f;
#pragma unroll
        for (int e = 0; e < EPL; ++e) {
            float tmp = fmaf(a1, m1f[e], a0 * m0f[e]);   // a0,a1 are SGPRs
            tmp  = fmaf(u_cur, wif[e], tmp);
            y[e] = fmaf(y[e], 0.8f, tmp);
            float ex = __builtin_amdgcn_exp2f(y[e]);
            float r  = fmaf(-2.0f, __builtin_amdgcn_rcpf(ex + 1.0f), 1.0f);
            p0 = fmaf(r, n0r[e], p0);
            p1 = fmaf(r, n1r[e], p1);
            pz = fmaf(r, wf[e], pz);
        }

        // 3 interleaved wave64 DPP tree-reductions (total lands in lane 63)
#define RED3(CTRL)                      \
        p0 = dpp_add_f32<CTRL>(p0);     \
        p1 = dpp_add_f32<CTRL>(p1);     \
        pz = dpp_add_f32<CTRL>(pz);
        RED3(0x111)  // row_shr:1
        RED3(0x112)  // row_shr:2
        RED3(0x114)  // row_shr:4
        RED3(0x118)  // row_shr:8
        RED3(0x142)  // row_bcast:15
        RED3(0x143)  // row_bcast:31
#undef RED3

        a0 = __int_as_float(__builtin_amdgcn_readlane(__float_as_int(p0), 63));
        a1 = __int_as_float(__builtin_amdgcn_readlane(__float_as_int(p1), 63));
        float zs = __int_as_float(__builtin_amdgcn_readlane(__float_as_int(pz), 63));

        // capture z_t on lane (t mod 64); coalesced 64-wide store every 64 steps
        zbuf = (lane == (t & 63)) ? zs : zbuf;
        if ((t & 63) == 63)
            z[(size_t)b * T_LEN + (t - 63) + lane] = zbuf;

        u_cur = u_next;
    }
}

extern "C" void kernel_launch(void* const* d_in, const int* in_sizes, int n_in,
                              void* d_out, int out_size, void* d_ws, size_t ws_size,
                              hipStream_t stream) {
    const float* u  = (const float*)d_in[0];
    const float* m  = (const float*)d_in[1];
    const float* n  = (const float*)d_in[2];
    const float* wi = (const float*)d_in[3];
    const float* w  = (const float*)d_in[4];
    float* z = (float*)d_out;

    dim3 grid(256), block(256);
    hipLaunchKernelGGL(rnn_lowrank_kernel, grid, block, 0, stream, u, m, n, wi, w, z);
}